// Round 8
// baseline (429.138 us; speedup 1.0000x reference)
//
#include <hip/hip_runtime.h>
#include <stdint.h>

#define NV 16384
#define BTQS (NV + 64)     // fp8 B-transpose row stride (bytes)
#define NSP 16             // K-split ways
#define KSL 1024           // K columns per slice
#define NIT 32             // main-loop iters per block (KSL/32)
#define LDSTR 1040         // LDS row stride bytes (1024+16: 2-way bank alias, free)
#define SCUP 16384.0f      // adj scale into fp8 range (exact pow2)
#define SCDN 6.103515625e-05f

typedef __attribute__((ext_vector_type(4))) float f32x4;

// prep: Z[i][c] = (h@W1)[i][c] fp32 ; Btq1[c][i] = fp8((h@L1)[i][c])
__global__ __launch_bounds__(256) void k_prep(
    const float* __restrict__ h, const float* __restrict__ W1,
    const float* __restrict__ L1, float* __restrict__ Z,
    unsigned char* __restrict__ Btq1) {
  __shared__ float Ws[4096], Ls[4096], hs[16 * 64];
  int tid = threadIdx.x;
  for (int i = tid; i < 4096; i += 256) { Ws[i] = W1[i]; Ls[i] = L1[i]; }
  int r = tid >> 6, c = tid & 63;
  int i0 = blockIdx.x << 4;
  #pragma unroll
  for (int m = 0; m < 4; ++m)
    hs[(r + 4 * m) * 64 + c] = h[(size_t)(i0 + r + 4 * m) * 64 + c];
  __syncthreads();
  float a1[4] = {0.f, 0.f, 0.f, 0.f};
  float a2[4] = {0.f, 0.f, 0.f, 0.f};
  #pragma unroll 8
  for (int k = 0; k < 64; ++k) {
    float wv = Ws[k * 64 + c];
    float lv = Ls[k * 64 + c];
    #pragma unroll
    for (int m = 0; m < 4; ++m) {
      float hv = hs[(r + 4 * m) * 64 + k];
      a1[m] += hv * wv;
      a2[m] += hv * lv;
    }
  }
  #pragma unroll
  for (int m = 0; m < 4; ++m) {
    int i = i0 + r + 4 * m;
    Z[(size_t)i * 64 + c] = a1[m];
    unsigned q = __builtin_amdgcn_cvt_pk_fp8_f32(a2[m], 0.0f, 0, false);
    Btq1[(size_t)c * BTQS + i] = (unsigned char)(q & 0xff);
  }
}

// Stage one 64x1024 fp8 B-slice into LDS (once per block). tid covers
// 16 units of 16B: unit u = tid + j*256, row = u>>6, col16 = u&63.
#define STAGE_SLICE(BLDS, BTQ, KB)                                       \
  {                                                                      \
    _Pragma("unroll")                                                    \
    for (int j = 0; j < 16; ++j) {                                       \
      int u = tid + j * 256;                                             \
      int r_ = u >> 6, c16 = u & 63;                                     \
      *(f32x4*)(BLDS + r_ * LDSTR + c16 * 16) =                          \
          *(const f32x4*)(BTQ + (size_t)r_ * BTQS + (KB) + c16 * 16);    \
    }                                                                    \
  }

// layer-1 big: P[yb] = adj[:, slice] @ B1[slice, :], fp8_fp8 MFMA.
// B-slice LDS-staged ONCE; main loop has NO barriers (no vmcnt(0) drains).
// adj packed to fp8 once; same reg feeds MFMA A and fragment-major adj8 store.
__global__ __launch_bounds__(256, 2) void k_adj1(
    const float* __restrict__ adj, const unsigned char* __restrict__ Btq,
    float* __restrict__ P, unsigned char* __restrict__ adj8) {
  __shared__ __align__(16) unsigned char Blds[64 * LDSTR];
  const int tid = threadIdx.x;
  const int lane = tid & 63;
  const int w = tid >> 6;
  const int l15 = lane & 15;
  const int kgrp = lane >> 4;
  const int xb = blockIdx.x;
  const int yb = blockIdx.y;
  const int row = (xb << 6) + (w << 4) + l15;
  const int kbase = yb << 10;                 // 1024 per slice

  STAGE_SLICE(Blds, Btq, kbase)

  const float* ap = adj + (size_t)row * NV + kbase + kgrp * 8;
  unsigned char* a8w = adj8 +
      ((((size_t)xb * NSP + yb) * 4 + w) * NIT) * 512 + (size_t)lane * 8;
  const int bofs0 = (l15 +  0) * LDSTR + kgrp * 8;
  const int bofs1 = (l15 + 16) * LDSTR + kgrp * 8;
  const int bofs2 = (l15 + 32) * LDSTR + kgrp * 8;
  const int bofs3 = (l15 + 48) * LDSTR + kgrp * 8;

  __syncthreads();

  // rolling depth-8 adj prefetch
  f32x4 aj0a, aj0b, aj1a, aj1b, aj2a, aj2b, aj3a, aj3b;
  f32x4 aj4a, aj4b, aj5a, aj5b, aj6a, aj6b, aj7a, aj7b;
  aj0a = *(const f32x4*)(ap +   0); aj0b = *(const f32x4*)(ap +   4);
  aj1a = *(const f32x4*)(ap +  32); aj1b = *(const f32x4*)(ap +  36);
  aj2a = *(const f32x4*)(ap +  64); aj2b = *(const f32x4*)(ap +  68);
  aj3a = *(const f32x4*)(ap +  96); aj3b = *(const f32x4*)(ap + 100);
  aj4a = *(const f32x4*)(ap + 128); aj4b = *(const f32x4*)(ap + 132);
  aj5a = *(const f32x4*)(ap + 160); aj5b = *(const f32x4*)(ap + 164);
  aj6a = *(const f32x4*)(ap + 192); aj6b = *(const f32x4*)(ap + 196);
  aj7a = *(const f32x4*)(ap + 224); aj7b = *(const f32x4*)(ap + 228);

  f32x4 acc0 = {0.f, 0.f, 0.f, 0.f};
  f32x4 acc1 = {0.f, 0.f, 0.f, 0.f};
  f32x4 acc2 = {0.f, 0.f, 0.f, 0.f};
  f32x4 acc3 = {0.f, 0.f, 0.f, 0.f};

#define ITER1(II, AJA, AJB)                                              \
  {                                                                      \
    unsigned pk0 = __builtin_amdgcn_cvt_pk_fp8_f32(AJA[0] * SCUP, AJA[1] * SCUP, 0, false); \
    pk0 = __builtin_amdgcn_cvt_pk_fp8_f32(AJA[2] * SCUP, AJA[3] * SCUP, pk0, true);         \
    unsigned pk1 = __builtin_amdgcn_cvt_pk_fp8_f32(AJB[0] * SCUP, AJB[1] * SCUP, 0, false); \
    pk1 = __builtin_amdgcn_cvt_pk_fp8_f32(AJB[2] * SCUP, AJB[3] * SCUP, pk1, true);         \
    unsigned long long av = (unsigned long long)pk0 | ((unsigned long long)pk1 << 32); \
    *(unsigned long long*)(a8w + (size_t)((t << 3) + (II)) * 512) = av;  \
    long long a_ = (long long)av;                                        \
    int ci = ((t << 3) + (II) + 8) & (NIT - 1);                          \
    AJA = *(const f32x4*)(ap + (size_t)ci * 32);                         \
    AJB = *(const f32x4*)(ap + (size_t)ci * 32 + 4);                     \
    long long b0 = *(const long long*)(bb + bofs0 + (II) * 32);          \
    long long b1 = *(const long long*)(bb + bofs1 + (II) * 32);          \
    long long b2 = *(const long long*)(bb + bofs2 + (II) * 32);          \
    long long b3 = *(const long long*)(bb + bofs3 + (II) * 32);          \
    acc0 = __builtin_amdgcn_mfma_f32_16x16x32_fp8_fp8(a_, b0, acc0, 0, 0, 0); \
    acc1 = __builtin_amdgcn_mfma_f32_16x16x32_fp8_fp8(a_, b1, acc1, 0, 0, 0); \
    acc2 = __builtin_amdgcn_mfma_f32_16x16x32_fp8_fp8(a_, b2, acc2, 0, 0, 0); \
    acc3 = __builtin_amdgcn_mfma_f32_16x16x32_fp8_fp8(a_, b3, acc3, 0, 0, 0); \
  }

  for (int t = 0; t < NIT / 8; ++t) {
    const unsigned char* bb = Blds + t * 256;
    ITER1(0, aj0a, aj0b)
    ITER1(1, aj1a, aj1b)
    ITER1(2, aj2a, aj2b)
    ITER1(3, aj3a, aj3b)
    ITER1(4, aj4a, aj4b)
    ITER1(5, aj5a, aj5b)
    ITER1(6, aj6a, aj6b)
    ITER1(7, aj7a, aj7b)
  }

  // D layout: col = lane&15 (+16*f), row = (lane>>4)*4 + reg  [m89-verified]
  int zr = (xb << 6) + (w << 4) + (kgrp << 2);
  float* pp = P + (size_t)yb * NV * 64 + (size_t)zr * 64 + l15;
  #pragma unroll
  for (int r = 0; r < 4; ++r) {
    pp[(size_t)r * 64 +  0] = acc0[r] * SCDN;
    pp[(size_t)r * 64 + 16] = acc1[r] * SCDN;
    pp[(size_t)r * 64 + 32] = acc2[r] * SCDN;
    pp[(size_t)r * 64 + 48] = acc3[r] * SCDN;
  }
#undef ITER1
}

// layer-2 big: P[yb] = (adj8 * 2^-14) @ B2, fp8_fp8. adj8 fragment-major.
__global__ __launch_bounds__(256, 2) void k_adj8(
    const unsigned char* __restrict__ adj8, const unsigned char* __restrict__ Btq,
    float* __restrict__ P) {
  __shared__ __align__(16) unsigned char Blds[64 * LDSTR];
  const int tid = threadIdx.x;
  const int lane = tid & 63;
  const int w = tid >> 6;
  const int l15 = lane & 15;
  const int kgrp = lane >> 4;
  const int xb = blockIdx.x;
  const int yb = blockIdx.y;
  const int kbase = yb << 10;

  STAGE_SLICE(Blds, Btq, kbase)

  const unsigned char* ap8 = adj8 +
      ((((size_t)xb * NSP + yb) * 4 + w) * NIT) * 512 + (size_t)lane * 8;
  const int bofs0 = (l15 +  0) * LDSTR + kgrp * 8;
  const int bofs1 = (l15 + 16) * LDSTR + kgrp * 8;
  const int bofs2 = (l15 + 32) * LDSTR + kgrp * 8;
  const int bofs3 = (l15 + 48) * LDSTR + kgrp * 8;

  __syncthreads();

  unsigned long long aj0, aj1, aj2, aj3, aj4, aj5, aj6, aj7;
  aj0 = *(const unsigned long long*)(ap8 +    0);
  aj1 = *(const unsigned long long*)(ap8 +  512);
  aj2 = *(const unsigned long long*)(ap8 + 1024);
  aj3 = *(const unsigned long long*)(ap8 + 1536);
  aj4 = *(const unsigned long long*)(ap8 + 2048);
  aj5 = *(const unsigned long long*)(ap8 + 2560);
  aj6 = *(const unsigned long long*)(ap8 + 3072);
  aj7 = *(const unsigned long long*)(ap8 + 3584);

  f32x4 acc0 = {0.f, 0.f, 0.f, 0.f};
  f32x4 acc1 = {0.f, 0.f, 0.f, 0.f};
  f32x4 acc2 = {0.f, 0.f, 0.f, 0.f};
  f32x4 acc3 = {0.f, 0.f, 0.f, 0.f};

#define ITER8(II, AJ)                                                    \
  {                                                                      \
    long long a_ = (long long)AJ;                                        \
    int ci = ((t << 3) + (II) + 8) & (NIT - 1);                          \
    AJ = *(const unsigned long long*)(ap8 + (size_t)ci * 512);           \
    long long b0 = *(const long long*)(bb + bofs0 + (II) * 32);          \
    long long b1 = *(const long long*)(bb + bofs1 + (II) * 32);          \
    long long b2 = *(const long long*)(bb + bofs2 + (II) * 32);          \
    long long b3 = *(const long long*)(bb + bofs3 + (II) * 32);          \
    acc0 = __builtin_amdgcn_mfma_f32_16x16x32_fp8_fp8(a_, b0, acc0, 0, 0, 0); \
    acc1 = __builtin_amdgcn_mfma_f32_16x16x32_fp8_fp8(a_, b1, acc1, 0, 0, 0); \
    acc2 = __builtin_amdgcn_mfma_f32_16x16x32_fp8_fp8(a_, b2, acc2, 0, 0, 0); \
    acc3 = __builtin_amdgcn_mfma_f32_16x16x32_fp8_fp8(a_, b3, acc3, 0, 0, 0); \
  }

  for (int t = 0; t < NIT / 8; ++t) {
    const unsigned char* bb = Blds + t * 256;
    ITER8(0, aj0)
    ITER8(1, aj1)
    ITER8(2, aj2)
    ITER8(3, aj3)
    ITER8(4, aj4)
    ITER8(5, aj5)
    ITER8(6, aj6)
    ITER8(7, aj7)
  }

  int zr = (xb << 6) + (w << 4) + (kgrp << 2);
  float* pp = P + (size_t)yb * NV * 64 + (size_t)zr * 64 + l15;
  #pragma unroll
  for (int r = 0; r < 4; ++r) {
    pp[(size_t)r * 64 +  0] = acc0[r] * SCDN;
    pp[(size_t)r * 64 + 16] = acc1[r] * SCDN;
    pp[(size_t)r * 64 + 32] = acc2[r] * SCDN;
    pp[(size_t)r * 64 + 48] = acc3[r] * SCDN;
  }
#undef ITER8
}

// mid: x = relu((Z+ΣP)*rw1[reg]+rb1[reg]); Z = x@W2; Btq2 = fp8((x@L2)^T)
__global__ __launch_bounds__(256) void k_mid(
    float* __restrict__ Z, const float* __restrict__ P,
    const int* __restrict__ reg,
    const float* __restrict__ rw1, const float* __restrict__ rb1,
    const float* __restrict__ W2, const float* __restrict__ L2,
    unsigned char* __restrict__ Btq2) {
  __shared__ float Ws[4096], Ls[4096], xs[16 * 64];
  int tid = threadIdx.x;
  for (int i = tid; i < 4096; i += 256) { Ws[i] = W2[i]; Ls[i] = L2[i]; }
  int r = tid >> 6, c = tid & 63;
  int i0 = blockIdx.x << 4;
  #pragma unroll
  for (int m = 0; m < 4; ++m) {
    int i = i0 + r + 4 * m;
    int ri = reg[i];
    size_t o = (size_t)i * 64 + c;
    float z = Z[o];
    #pragma unroll
    for (int j = 0; j < NSP; ++j) z += P[(size_t)j * NV * 64 + o];
    float x = z * rw1[ri * 64 + c] + rb1[ri * 64 + c];
    xs[(r + 4 * m) * 64 + c] = fmaxf(x, 0.f);
  }
  __syncthreads();
  float a1[4] = {0.f, 0.f, 0.f, 0.f};
  float a2[4] = {0.f, 0.f, 0.f, 0.f};
  #pragma unroll 8
  for (int k = 0; k < 64; ++k) {
    float wv = Ws[k * 64 + c];
    float lv = Ls[k * 64 + c];
    #pragma unroll
    for (int m = 0; m < 4; ++m) {
      float xv = xs[(r + 4 * m) * 64 + k];
      a1[m] += xv * wv;
      a2[m] += xv * lv;
    }
  }
  #pragma unroll
  for (int m = 0; m < 4; ++m) {
    int i = i0 + r + 4 * m;
    Z[(size_t)i * 64 + c] = a1[m];
    unsigned q = __builtin_amdgcn_cvt_pk_fp8_f32(a2[m], 0.0f, 0, false);
    Btq2[(size_t)c * BTQS + i] = (unsigned char)(q & 0xff);
  }
}

// out: x2 = relu((Z+ΣP)*rw2[reg]+rb2[reg]); out = x2 @ Wout^T + bout
__global__ __launch_bounds__(256) void k_out(
    const float* __restrict__ Z, const float* __restrict__ P,
    const int* __restrict__ reg,
    const float* __restrict__ rw2, const float* __restrict__ rb2,
    const float* __restrict__ Wout, const float* __restrict__ bout,
    float* __restrict__ out) {
  __shared__ float xs[16 * 64];
  int tid = threadIdx.x;
  int r = tid >> 6, c = tid & 63;
  int i0 = blockIdx.x << 4;
  #pragma unroll
  for (int m = 0; m < 4; ++m) {
    int i = i0 + r + 4 * m;
    int ri = reg[i];
    size_t o = (size_t)i * 64 + c;
    float z = Z[o];
    #pragma unroll
    for (int j = 0; j < NSP; ++j) z += P[(size_t)j * NV * 64 + o];
    float x = z * rw2[ri * 64 + c] + rb2[ri * 64 + c];
    xs[(r + 4 * m) * 64 + c] = fmaxf(x, 0.f);
  }
  __syncthreads();
  if (c < 8) {
    #pragma unroll
    for (int m = 0; m < 4; ++m) {
      int i = i0 + r + 4 * m;
      float a = bout[c];
      #pragma unroll 8
      for (int k = 0; k < 64; ++k) a += xs[(r + 4 * m) * 64 + k] * Wout[c * 64 + k];
      out[(size_t)i * 8 + c] = a;
    }
  }
}

extern "C" void kernel_launch(void* const* d_in, const int* in_sizes, int n_in,
                              void* d_out, int out_size, void* d_ws, size_t ws_size,
                              hipStream_t stream) {
  const float* h    = (const float*)d_in[0];
  const float* adj  = (const float*)d_in[1];
  const int*   reg  = (const int*)d_in[2];
  const float* W1   = (const float*)d_in[3];
  const float* L1   = (const float*)d_in[4];
  const float* rw1  = (const float*)d_in[5];
  const float* rb1  = (const float*)d_in[6];
  const float* W2   = (const float*)d_in[7];
  const float* L2   = (const float*)d_in[8];
  const float* rw2  = (const float*)d_in[9];
  const float* rb2  = (const float*)d_in[10];
  const float* Wout = (const float*)d_in[11];
  const float* bout = (const float*)d_in[12];
  float* out = (float*)d_out;

  char* ws = (char*)d_ws;
  float* Z            = (float*)(ws);                                 // 4 MB @ 0
  unsigned char* Btq1 = (unsigned char*)(ws + ((size_t)4  << 20));    // ~1.06 MB
  float* P            = (float*)(ws + ((size_t)8  << 20));            // 64 MB (16 slices)
  unsigned char* Btq2 = (unsigned char*)(ws + ((size_t)76 << 20));    // ~1.06 MB
  unsigned char* adj8 = (unsigned char*)(ws + ((size_t)80 << 20));    // 256 MB

  k_prep<<<NV / 16, 256, 0, stream>>>(h, W1, L1, Z, Btq1);
  k_adj1<<<dim3(NV / 64, NSP), 256, 0, stream>>>(adj, Btq1, P, adj8);
  k_mid<<<NV / 16, 256, 0, stream>>>(Z, P, reg, rw1, rb1, W2, L2, Btq2);
  k_adj8<<<dim3(NV / 64, NSP), 256, 0, stream>>>(adj8, Btq2, P);
  k_out<<<NV / 16, 256, 0, stream>>>(Z, P, reg, rw2, rb2, Wout, bout, out);
}

// Round 9
// 368.053 us; speedup vs baseline: 1.1660x; 1.1660x over previous
//
#include <hip/hip_runtime.h>
#include <stdint.h>

#define NV 16384
#define BTQS (NV + 64)     // fp8 B-transpose row stride (bytes)
#define BK 256             // K-chunk (columns per LDS stage)
#define LDST8 272          // fp8 LDS row stride (bytes)
#define NCH 16             // chunks per K-quarter: 4096/256
#define SCUP 16384.0f      // adj scale into fp8 range (exact pow2)
#define SCDN 6.103515625e-05f

typedef __attribute__((ext_vector_type(4))) float f32x4;
typedef __attribute__((ext_vector_type(4))) unsigned u32x4;

// prep: Z[i][c] = (h@W1)[i][c] fp32 ; Btq1[c][i] = fp8((h@L1)[i][c])
__global__ __launch_bounds__(256) void k_prep(
    const float* __restrict__ h, const float* __restrict__ W1,
    const float* __restrict__ L1, float* __restrict__ Z,
    unsigned char* __restrict__ Btq1) {
  __shared__ float Ws[4096], Ls[4096], hs[16 * 64];
  int tid = threadIdx.x;
  for (int i = tid; i < 4096; i += 256) { Ws[i] = W1[i]; Ls[i] = L1[i]; }
  int r = tid >> 6, c = tid & 63;
  int i0 = blockIdx.x << 4;
  #pragma unroll
  for (int m = 0; m < 4; ++m)
    hs[(r + 4 * m) * 64 + c] = h[(size_t)(i0 + r + 4 * m) * 64 + c];
  __syncthreads();
  float a1[4] = {0.f, 0.f, 0.f, 0.f};
  float a2[4] = {0.f, 0.f, 0.f, 0.f};
  #pragma unroll 8
  for (int k = 0; k < 64; ++k) {
    float wv = Ws[k * 64 + c];
    float lv = Ls[k * 64 + c];
    #pragma unroll
    for (int m = 0; m < 4; ++m) {
      float hv = hs[(r + 4 * m) * 64 + k];
      a1[m] += hv * wv;
      a2[m] += hv * lv;
    }
  }
  #pragma unroll
  for (int m = 0; m < 4; ++m) {
    int i = i0 + r + 4 * m;
    Z[(size_t)i * 64 + c] = a1[m];
    unsigned q = __builtin_amdgcn_cvt_pk_fp8_f32(a2[m], 0.0f, 0, false);
    Btq1[(size_t)c * BTQS + i] = (unsigned char)(q & 0xff);
  }
}

// layer-1 big: P[yb] = adj @ B1, fp8_fp8 MFMA. Packs adj*2^14 to fp8 once; the
// packed reg feeds the MFMA A-operand AND a PAIR-MAJOR adj8 store:
// pair p of wave w: offset = (((xb*4+yb)*4+w)*64 + p)*1024 + lane*16
// -> 1KB contiguous per wave-store (16B/lane), nontemporal (no L2 pollution).
__global__ __launch_bounds__(256, 4) void k_adj1(
    const float* __restrict__ adj, const unsigned char* __restrict__ Btq,
    float* __restrict__ P, unsigned char* __restrict__ adj8) {
  __shared__ __align__(16) unsigned char Blds[2 * 64 * LDST8];
  const int tid = threadIdx.x;
  const int lane = tid & 63;
  const int w = tid >> 6;
  const int l15 = lane & 15;
  const int kgrp = lane >> 4;
  const int xb = blockIdx.x;
  const int yb = blockIdx.y;
  const int row = (xb << 6) + (w << 4) + l15;
  const int kbase = yb << 12;                 // 4096 per quarter

  const int srow = tid >> 4;
  const int sc16 = tid & 15;
  const unsigned char* sbase = Btq + (size_t)srow * BTQS + kbase + sc16 * 16;
  unsigned char* lbase = Blds + srow * LDST8 + sc16 * 16;

  const float* ap = adj + (size_t)row * NV + kbase + kgrp * 8;
  unsigned char* a8w = adj8 +
      ((((size_t)xb * 4 + yb) * 4 + w) * 64) * 1024 + (size_t)lane * 16;
  const int bofs0 = (l15 +  0) * LDST8 + kgrp * 8;
  const int bofs1 = (l15 + 16) * LDST8 + kgrp * 8;
  const int bofs2 = (l15 + 32) * LDST8 + kgrp * 8;
  const int bofs3 = (l15 + 48) * LDST8 + kgrp * 8;

  f32x4 sr0, sr1, sr2, sr3;
#define STAGE_LOAD8(KC)                                                  \
  { const unsigned char* s_ = sbase + (KC);                              \
    sr0 = *(const f32x4*)(s_);                                           \
    sr1 = *(const f32x4*)(s_ + (size_t)16 * BTQS);                       \
    sr2 = *(const f32x4*)(s_ + (size_t)32 * BTQS);                       \
    sr3 = *(const f32x4*)(s_ + (size_t)48 * BTQS); }
#define STAGE_WRITE8(BUF)                                                \
  { unsigned char* d_ = lbase + (BUF) * (64 * LDST8);                    \
    *(f32x4*)(d_) = sr0;                                                 \
    *(f32x4*)(d_ + 16 * LDST8) = sr1;                                    \
    *(f32x4*)(d_ + 32 * LDST8) = sr2;                                    \
    *(f32x4*)(d_ + 48 * LDST8) = sr3; }

  f32x4 aj0a, aj0b, aj1a, aj1b, aj2a, aj2b, aj3a, aj3b;

  STAGE_LOAD8(0);
  aj0a = *(const f32x4*)(ap +   0); aj0b = *(const f32x4*)(ap +   4);
  aj1a = *(const f32x4*)(ap +  32); aj1b = *(const f32x4*)(ap +  36);
  aj2a = *(const f32x4*)(ap +  64); aj2b = *(const f32x4*)(ap +  68);
  aj3a = *(const f32x4*)(ap +  96); aj3b = *(const f32x4*)(ap + 100);
  STAGE_WRITE8(0);
  __syncthreads();

  f32x4 acc0 = {0.f, 0.f, 0.f, 0.f};
  f32x4 acc1 = {0.f, 0.f, 0.f, 0.f};
  f32x4 acc2 = {0.f, 0.f, 0.f, 0.f};
  f32x4 acc3 = {0.f, 0.f, 0.f, 0.f};

  unsigned pk0_sv = 0, pk1_sv = 0;

#define PACK(AJA, AJB, PK0, PK1)                                         \
    unsigned PK0 = __builtin_amdgcn_cvt_pk_fp8_f32(AJA[0] * SCUP, AJA[1] * SCUP, 0, false); \
    PK0 = __builtin_amdgcn_cvt_pk_fp8_f32(AJA[2] * SCUP, AJA[3] * SCUP, PK0, true);         \
    unsigned PK1 = __builtin_amdgcn_cvt_pk_fp8_f32(AJB[0] * SCUP, AJB[1] * SCUP, 0, false); \
    PK1 = __builtin_amdgcn_cvt_pk_fp8_f32(AJB[2] * SCUP, AJB[3] * SCUP, PK1, true);

#define MFMA4(AV)                                                        \
    { long long a_ = (long long)(AV);                                    \
      long long b0 = *(const long long*)(bb + bofs0 + (II) * 32);        \
      long long b1 = *(const long long*)(bb + bofs1 + (II) * 32);        \
      long long b2 = *(const long long*)(bb + bofs2 + (II) * 32);        \
      long long b3 = *(const long long*)(bb + bofs3 + (II) * 32);        \
      acc0 = __builtin_amdgcn_mfma_f32_16x16x32_fp8_fp8(a_, b0, acc0, 0, 0, 0); \
      acc1 = __builtin_amdgcn_mfma_f32_16x16x32_fp8_fp8(a_, b1, acc1, 0, 0, 0); \
      acc2 = __builtin_amdgcn_mfma_f32_16x16x32_fp8_fp8(a_, b2, acc2, 0, 0, 0); \
      acc3 = __builtin_amdgcn_mfma_f32_16x16x32_fp8_fp8(a_, b3, acc3, 0, 0, 0); }

// even ITER: pack, save halves, prefetch, MFMA
#define ITER1E(IIV, AJA, AJB)                                            \
  { const int II = (IIV);                                                \
    PACK(AJA, AJB, pk0, pk1)                                             \
    pk0_sv = pk0; pk1_sv = pk1;                                          \
    unsigned long long av = (unsigned long long)pk0 | ((unsigned long long)pk1 << 32); \
    int ci = ((t << 3) + II + 4) & 127;                                  \
    AJA = *(const f32x4*)(ap + (size_t)ci * 32);                         \
    AJB = *(const f32x4*)(ap + (size_t)ci * 32 + 4);                     \
    MFMA4(av)                                                            \
  }
// odd ITER: pack, store the (even,odd) pair 16B/lane nontemporal, prefetch, MFMA
#define ITER1O(IIV, AJA, AJB)                                            \
  { const int II = (IIV);                                                \
    PACK(AJA, AJB, pk0, pk1)                                             \
    u32x4 pv; pv[0] = pk0_sv; pv[1] = pk1_sv; pv[2] = pk0; pv[3] = pk1;  \
    __builtin_nontemporal_store(pv,                                      \
        (u32x4*)(a8w + (size_t)((t << 2) + (II >> 1)) * 1024));          \
    unsigned long long av = (unsigned long long)pk0 | ((unsigned long long)pk1 << 32); \
    int ci = ((t << 3) + II + 4) & 127;                                  \
    AJA = *(const f32x4*)(ap + (size_t)ci * 32);                         \
    AJB = *(const f32x4*)(ap + (size_t)ci * 32 + 4);                     \
    MFMA4(av)                                                            \
  }

  for (int t = 0; t < NCH; ++t) {
    const unsigned char* bb = Blds + (t & 1) * (64 * LDST8);
    if (t + 1 < NCH) STAGE_LOAD8((t + 1) * BK);
    ITER1E(0, aj0a, aj0b)
    ITER1O(1, aj1a, aj1b)
    ITER1E(2, aj2a, aj2b)
    ITER1O(3, aj3a, aj3b)
    ITER1E(4, aj0a, aj0b)
    ITER1O(5, aj1a, aj1b)
    ITER1E(6, aj2a, aj2b)
    ITER1O(7, aj3a, aj3b)
    if (t + 1 < NCH) STAGE_WRITE8((t + 1) & 1);
    __syncthreads();
  }

  // D layout: col = lane&15 (+16*f), row = (lane>>4)*4 + reg  [m89-verified]
  int zr = (xb << 6) + (w << 4) + (kgrp << 2);
  float* pp = P + (size_t)yb * NV * 64 + (size_t)zr * 64 + l15;
  #pragma unroll
  for (int r = 0; r < 4; ++r) {
    pp[(size_t)r * 64 +  0] = acc0[r] * SCDN;
    pp[(size_t)r * 64 + 16] = acc1[r] * SCDN;
    pp[(size_t)r * 64 + 32] = acc2[r] * SCDN;
    pp[(size_t)r * 64 + 48] = acc3[r] * SCDN;
  }
#undef ITER1E
#undef ITER1O
#undef PACK
#undef MFMA4
}

// layer-2 big: P[yb] = (adj8 * 2^-14) @ B2 (fp8_fp8). adj8 pair-major:
// one 16B/lane load supplies TWO ITERs' A-fragments.
__global__ __launch_bounds__(256, 4) void k_adj8(
    const unsigned char* __restrict__ adj8, const unsigned char* __restrict__ Btq,
    float* __restrict__ P) {
  __shared__ __align__(16) unsigned char Blds[2 * 64 * LDST8];
  const int tid = threadIdx.x;
  const int lane = tid & 63;
  const int w = tid >> 6;
  const int l15 = lane & 15;
  const int kgrp = lane >> 4;
  const int xb = blockIdx.x;
  const int yb = blockIdx.y;
  const int kbase = yb << 12;

  const int srow = tid >> 4;
  const int sc16 = tid & 15;
  const unsigned char* sbase = Btq + (size_t)srow * BTQS + kbase + sc16 * 16;
  unsigned char* lbase = Blds + srow * LDST8 + sc16 * 16;

  const unsigned char* ap8 = adj8 +
      ((((size_t)xb * 4 + yb) * 4 + w) * 64) * 1024 + (size_t)lane * 16;
  const int bofs0 = (l15 +  0) * LDST8 + kgrp * 8;
  const int bofs1 = (l15 + 16) * LDST8 + kgrp * 8;
  const int bofs2 = (l15 + 32) * LDST8 + kgrp * 8;
  const int bofs3 = (l15 + 48) * LDST8 + kgrp * 8;

  f32x4 sr0, sr1, sr2, sr3;

  STAGE_LOAD8(0);
  u32x4 pr0 = *(const u32x4*)(ap8 +    0);
  u32x4 pr1 = *(const u32x4*)(ap8 + 1024);
  u32x4 pr2 = *(const u32x4*)(ap8 + 2048);
  u32x4 pr3 = *(const u32x4*)(ap8 + 3072);
  STAGE_WRITE8(0);
  __syncthreads();

  f32x4 acc0 = {0.f, 0.f, 0.f, 0.f};
  f32x4 acc1 = {0.f, 0.f, 0.f, 0.f};
  f32x4 acc2 = {0.f, 0.f, 0.f, 0.f};
  f32x4 acc3 = {0.f, 0.f, 0.f, 0.f};

#define MFMA4A(AV, II)                                                   \
    { long long a_ = (AV);                                               \
      long long b0 = *(const long long*)(bb + bofs0 + (II) * 32);        \
      long long b1 = *(const long long*)(bb + bofs1 + (II) * 32);        \
      long long b2 = *(const long long*)(bb + bofs2 + (II) * 32);        \
      long long b3 = *(const long long*)(bb + bofs3 + (II) * 32);        \
      acc0 = __builtin_amdgcn_mfma_f32_16x16x32_fp8_fp8(a_, b0, acc0, 0, 0, 0); \
      acc1 = __builtin_amdgcn_mfma_f32_16x16x32_fp8_fp8(a_, b1, acc1, 0, 0, 0); \
      acc2 = __builtin_amdgcn_mfma_f32_16x16x32_fp8_fp8(a_, b2, acc2, 0, 0, 0); \
      acc3 = __builtin_amdgcn_mfma_f32_16x16x32_fp8_fp8(a_, b3, acc3, 0, 0, 0); }

#define PITER(PP, PR)                                                    \
  {                                                                      \
    long long aE = (long long)(((unsigned long long)PR[1] << 32) | PR[0]); \
    long long aO = (long long)(((unsigned long long)PR[3] << 32) | PR[2]); \
    int ci = ((t << 2) + (PP) + 4) & 63;                                 \
    PR = *(const u32x4*)(ap8 + (size_t)ci * 1024);                       \
    MFMA4A(aE, 2 * (PP))                                                 \
    MFMA4A(aO, 2 * (PP) + 1)                                             \
  }

  for (int t = 0; t < NCH; ++t) {
    const unsigned char* bb = Blds + (t & 1) * (64 * LDST8);
    if (t + 1 < NCH) STAGE_LOAD8((t + 1) * BK);
    PITER(0, pr0)
    PITER(1, pr1)
    PITER(2, pr2)
    PITER(3, pr3)
    if (t + 1 < NCH) STAGE_WRITE8((t + 1) & 1);
    __syncthreads();
  }

  int zr = (xb << 6) + (w << 4) + (kgrp << 2);
  float* pp = P + (size_t)yb * NV * 64 + (size_t)zr * 64 + l15;
  #pragma unroll
  for (int r = 0; r < 4; ++r) {
    pp[(size_t)r * 64 +  0] = acc0[r] * SCDN;
    pp[(size_t)r * 64 + 16] = acc1[r] * SCDN;
    pp[(size_t)r * 64 + 32] = acc2[r] * SCDN;
    pp[(size_t)r * 64 + 48] = acc3[r] * SCDN;
  }
#undef PITER
#undef MFMA4A
#undef STAGE_LOAD8
#undef STAGE_WRITE8
}

// mid: x = relu((Z+ΣP)*rw1[reg]+rb1[reg]); Z = x@W2; Btq2 = fp8((x@L2)^T)
__global__ __launch_bounds__(256) void k_mid(
    float* __restrict__ Z, const float* __restrict__ P,
    const int* __restrict__ reg,
    const float* __restrict__ rw1, const float* __restrict__ rb1,
    const float* __restrict__ W2, const float* __restrict__ L2,
    unsigned char* __restrict__ Btq2) {
  __shared__ float Ws[4096], Ls[4096], xs[16 * 64];
  int tid = threadIdx.x;
  for (int i = tid; i < 4096; i += 256) { Ws[i] = W2[i]; Ls[i] = L2[i]; }
  int r = tid >> 6, c = tid & 63;
  int i0 = blockIdx.x << 4;
  #pragma unroll
  for (int m = 0; m < 4; ++m) {
    int i = i0 + r + 4 * m;
    int ri = reg[i];
    size_t o = (size_t)i * 64 + c;
    float z = Z[o] + P[o] + P[(size_t)NV * 64 + o] +
              P[(size_t)2 * NV * 64 + o] + P[(size_t)3 * NV * 64 + o];
    float x = z * rw1[ri * 64 + c] + rb1[ri * 64 + c];
    xs[(r + 4 * m) * 64 + c] = fmaxf(x, 0.f);
  }
  __syncthreads();
  float a1[4] = {0.f, 0.f, 0.f, 0.f};
  float a2[4] = {0.f, 0.f, 0.f, 0.f};
  #pragma unroll 8
  for (int k = 0; k < 64; ++k) {
    float wv = Ws[k * 64 + c];
    float lv = Ls[k * 64 + c];
    #pragma unroll
    for (int m = 0; m < 4; ++m) {
      float xv = xs[(r + 4 * m) * 64 + k];
      a1[m] += xv * wv;
      a2[m] += xv * lv;
    }
  }
  #pragma unroll
  for (int m = 0; m < 4; ++m) {
    int i = i0 + r + 4 * m;
    Z[(size_t)i * 64 + c] = a1[m];
    unsigned q = __builtin_amdgcn_cvt_pk_fp8_f32(a2[m], 0.0f, 0, false);
    Btq2[(size_t)c * BTQS + i] = (unsigned char)(q & 0xff);
  }
}

// out: x2 = relu((Z+ΣP)*rw2[reg]+rb2[reg]); out = x2 @ Wout^T + bout
__global__ __launch_bounds__(256) void k_out(
    const float* __restrict__ Z, const float* __restrict__ P,
    const int* __restrict__ reg,
    const float* __restrict__ rw2, const float* __restrict__ rb2,
    const float* __restrict__ Wout, const float* __restrict__ bout,
    float* __restrict__ out) {
  __shared__ float xs[16 * 64];
  int tid = threadIdx.x;
  int r = tid >> 6, c = tid & 63;
  int i0 = blockIdx.x << 4;
  #pragma unroll
  for (int m = 0; m < 4; ++m) {
    int i = i0 + r + 4 * m;
    int ri = reg[i];
    size_t o = (size_t)i * 64 + c;
    float z = Z[o] + P[o] + P[(size_t)NV * 64 + o] +
              P[(size_t)2 * NV * 64 + o] + P[(size_t)3 * NV * 64 + o];
    float x = z * rw2[ri * 64 + c] + rb2[ri * 64 + c];
    xs[(r + 4 * m) * 64 + c] = fmaxf(x, 0.f);
  }
  __syncthreads();
  if (c < 8) {
    #pragma unroll
    for (int m = 0; m < 4; ++m) {
      int i = i0 + r + 4 * m;
      float a = bout[c];
      #pragma unroll 8
      for (int k = 0; k < 64; ++k) a += xs[(r + 4 * m) * 64 + k] * Wout[c * 64 + k];
      out[(size_t)i * 8 + c] = a;
    }
  }
}

extern "C" void kernel_launch(void* const* d_in, const int* in_sizes, int n_in,
                              void* d_out, int out_size, void* d_ws, size_t ws_size,
                              hipStream_t stream) {
  const float* h    = (const float*)d_in[0];
  const float* adj  = (const float*)d_in[1];
  const int*   reg  = (const int*)d_in[2];
  const float* W1   = (const float*)d_in[3];
  const float* L1   = (const float*)d_in[4];
  const float* rw1  = (const float*)d_in[5];
  const float* rb1  = (const float*)d_in[6];
  const float* W2   = (const float*)d_in[7];
  const float* L2   = (const float*)d_in[8];
  const float* rw2  = (const float*)d_in[9];
  const float* rb2  = (const float*)d_in[10];
  const float* Wout = (const float*)d_in[11];
  const float* bout = (const float*)d_in[12];
  float* out = (float*)d_out;

  char* ws = (char*)d_ws;
  float* Z            = (float*)(ws);                                 // 4 MB @ 0
  unsigned char* Btq1 = (unsigned char*)(ws + ((size_t)4  << 20));    // ~1.06 MB
  float* P            = (float*)(ws + ((size_t)8  << 20));            // 16 MB (4 slices)
  unsigned char* Btq2 = (unsigned char*)(ws + ((size_t)24 << 20));    // ~1.06 MB
  unsigned char* adj8 = (unsigned char*)(ws + ((size_t)28 << 20));    // 256 MB

  k_prep<<<NV / 16, 256, 0, stream>>>(h, W1, L1, Z, Btq1);
  k_adj1<<<dim3(NV / 64, 4), 256, 0, stream>>>(adj, Btq1, P, adj8);
  k_mid<<<NV / 16, 256, 0, stream>>>(Z, P, reg, rw1, rb1, W2, L2, Btq2);
  k_adj8<<<dim3(NV / 64, 4), 256, 0, stream>>>(adj8, Btq2, P);
  k_out<<<NV / 16, 256, 0, stream>>>(Z, P, reg, rw2, rb2, Wout, bout, out);
}

// Round 10
// 366.961 us; speedup vs baseline: 1.1694x; 1.0030x over previous
//
#include <hip/hip_runtime.h>
#include <stdint.h>

#define NV 16384
#define BTQS (NV + 64)     // fp8 B-transpose row stride (bytes)
#define BK 256             // K-chunk (columns per LDS stage)
#define LDST8 272          // fp8 LDS row stride (bytes)
#define NCH 16             // chunks per K-quarter: 4096/256
#define SCUP 16384.0f      // adj scale into fp8 range (exact pow2)
#define SCDN 6.103515625e-05f

typedef __attribute__((ext_vector_type(4))) float f32x4;
typedef __attribute__((ext_vector_type(4))) unsigned u32x4;

// prep: Z[i][c] = (h@W1)[i][c] fp32 ; Btq1[c][i] = fp8((h@L1)[i][c])
__global__ __launch_bounds__(256) void k_prep(
    const float* __restrict__ h, const float* __restrict__ W1,
    const float* __restrict__ L1, float* __restrict__ Z,
    unsigned char* __restrict__ Btq1) {
  __shared__ float Ws[4096], Ls[4096], hs[16 * 64];
  int tid = threadIdx.x;
  for (int i = tid; i < 4096; i += 256) { Ws[i] = W1[i]; Ls[i] = L1[i]; }
  int r = tid >> 6, c = tid & 63;
  int i0 = blockIdx.x << 4;
  #pragma unroll
  for (int m = 0; m < 4; ++m)
    hs[(r + 4 * m) * 64 + c] = h[(size_t)(i0 + r + 4 * m) * 64 + c];
  __syncthreads();
  float a1[4] = {0.f, 0.f, 0.f, 0.f};
  float a2[4] = {0.f, 0.f, 0.f, 0.f};
  #pragma unroll 8
  for (int k = 0; k < 64; ++k) {
    float wv = Ws[k * 64 + c];
    float lv = Ls[k * 64 + c];
    #pragma unroll
    for (int m = 0; m < 4; ++m) {
      float hv = hs[(r + 4 * m) * 64 + k];
      a1[m] += hv * wv;
      a2[m] += hv * lv;
    }
  }
  #pragma unroll
  for (int m = 0; m < 4; ++m) {
    int i = i0 + r + 4 * m;
    Z[(size_t)i * 64 + c] = a1[m];
    unsigned q = __builtin_amdgcn_cvt_pk_fp8_f32(a2[m], 0.0f, 0, false);
    Btq1[(size_t)c * BTQS + i] = (unsigned char)(q & 0xff);
  }
}

// layer-1 big: P[yb] = adj @ B1, fp8_fp8 MFMA. adj loads NONTEMPORAL (zero
// reuse -> evict-first, keep Btq resident in L2). Packs adj*2^14 to fp8 once;
// packed reg feeds MFMA A and the PAIR-MAJOR nontemporal adj8 store
// (pair p of wave w: offset = (((xb*4+yb)*4+w)*64 + p)*1024 + lane*16).
__global__ __launch_bounds__(256, 4) void k_adj1(
    const float* __restrict__ adj, const unsigned char* __restrict__ Btq,
    float* __restrict__ P, unsigned char* __restrict__ adj8) {
  __shared__ __align__(16) unsigned char Blds[2 * 64 * LDST8];
  const int tid = threadIdx.x;
  const int lane = tid & 63;
  const int w = tid >> 6;
  const int l15 = lane & 15;
  const int kgrp = lane >> 4;
  const int xb = blockIdx.x;
  const int yb = blockIdx.y;
  const int row = (xb << 6) + (w << 4) + l15;
  const int kbase = yb << 12;                 // 4096 per quarter

  const int srow = tid >> 4;
  const int sc16 = tid & 15;
  const unsigned char* sbase = Btq + (size_t)srow * BTQS + kbase + sc16 * 16;
  unsigned char* lbase = Blds + srow * LDST8 + sc16 * 16;

  const float* ap = adj + (size_t)row * NV + kbase + kgrp * 8;
  unsigned char* a8w = adj8 +
      ((((size_t)xb * 4 + yb) * 4 + w) * 64) * 1024 + (size_t)lane * 16;
  const int bofs0 = (l15 +  0) * LDST8 + kgrp * 8;
  const int bofs1 = (l15 + 16) * LDST8 + kgrp * 8;
  const int bofs2 = (l15 + 32) * LDST8 + kgrp * 8;
  const int bofs3 = (l15 + 48) * LDST8 + kgrp * 8;

  f32x4 sr0, sr1, sr2, sr3;
#define STAGE_LOAD8(KC)                                                  \
  { const unsigned char* s_ = sbase + (KC);                              \
    sr0 = *(const f32x4*)(s_);                                           \
    sr1 = *(const f32x4*)(s_ + (size_t)16 * BTQS);                       \
    sr2 = *(const f32x4*)(s_ + (size_t)32 * BTQS);                       \
    sr3 = *(const f32x4*)(s_ + (size_t)48 * BTQS); }
#define STAGE_WRITE8(BUF)                                                \
  { unsigned char* d_ = lbase + (BUF) * (64 * LDST8);                    \
    *(f32x4*)(d_) = sr0;                                                 \
    *(f32x4*)(d_ + 16 * LDST8) = sr1;                                    \
    *(f32x4*)(d_ + 32 * LDST8) = sr2;                                    \
    *(f32x4*)(d_ + 48 * LDST8) = sr3; }

  f32x4 aj0a, aj0b, aj1a, aj1b, aj2a, aj2b, aj3a, aj3b;

  STAGE_LOAD8(0);
  aj0a = __builtin_nontemporal_load((const f32x4*)(ap +   0));
  aj0b = __builtin_nontemporal_load((const f32x4*)(ap +   4));
  aj1a = __builtin_nontemporal_load((const f32x4*)(ap +  32));
  aj1b = __builtin_nontemporal_load((const f32x4*)(ap +  36));
  aj2a = __builtin_nontemporal_load((const f32x4*)(ap +  64));
  aj2b = __builtin_nontemporal_load((const f32x4*)(ap +  68));
  aj3a = __builtin_nontemporal_load((const f32x4*)(ap +  96));
  aj3b = __builtin_nontemporal_load((const f32x4*)(ap + 100));
  STAGE_WRITE8(0);
  __syncthreads();

  f32x4 acc0 = {0.f, 0.f, 0.f, 0.f};
  f32x4 acc1 = {0.f, 0.f, 0.f, 0.f};
  f32x4 acc2 = {0.f, 0.f, 0.f, 0.f};
  f32x4 acc3 = {0.f, 0.f, 0.f, 0.f};

  unsigned pk0_sv = 0, pk1_sv = 0;

#define PACK(AJA, AJB, PK0, PK1)                                         \
    unsigned PK0 = __builtin_amdgcn_cvt_pk_fp8_f32(AJA[0] * SCUP, AJA[1] * SCUP, 0, false); \
    PK0 = __builtin_amdgcn_cvt_pk_fp8_f32(AJA[2] * SCUP, AJA[3] * SCUP, PK0, true);         \
    unsigned PK1 = __builtin_amdgcn_cvt_pk_fp8_f32(AJB[0] * SCUP, AJB[1] * SCUP, 0, false); \
    PK1 = __builtin_amdgcn_cvt_pk_fp8_f32(AJB[2] * SCUP, AJB[3] * SCUP, PK1, true);

#define MFMA4(AV)                                                        \
    { long long a_ = (long long)(AV);                                    \
      long long b0 = *(const long long*)(bb + bofs0 + (II) * 32);        \
      long long b1 = *(const long long*)(bb + bofs1 + (II) * 32);        \
      long long b2 = *(const long long*)(bb + bofs2 + (II) * 32);        \
      long long b3 = *(const long long*)(bb + bofs3 + (II) * 32);        \
      acc0 = __builtin_amdgcn_mfma_f32_16x16x32_fp8_fp8(a_, b0, acc0, 0, 0, 0); \
      acc1 = __builtin_amdgcn_mfma_f32_16x16x32_fp8_fp8(a_, b1, acc1, 0, 0, 0); \
      acc2 = __builtin_amdgcn_mfma_f32_16x16x32_fp8_fp8(a_, b2, acc2, 0, 0, 0); \
      acc3 = __builtin_amdgcn_mfma_f32_16x16x32_fp8_fp8(a_, b3, acc3, 0, 0, 0); }

// even ITER: pack, save halves, prefetch (NT), MFMA
#define ITER1E(IIV, AJA, AJB)                                            \
  { const int II = (IIV);                                                \
    PACK(AJA, AJB, pk0, pk1)                                             \
    pk0_sv = pk0; pk1_sv = pk1;                                          \
    unsigned long long av = (unsigned long long)pk0 | ((unsigned long long)pk1 << 32); \
    int ci = ((t << 3) + II + 4) & 127;                                  \
    AJA = __builtin_nontemporal_load((const f32x4*)(ap + (size_t)ci * 32));     \
    AJB = __builtin_nontemporal_load((const f32x4*)(ap + (size_t)ci * 32 + 4)); \
    MFMA4(av)                                                            \
  }
// odd ITER: pack, store the (even,odd) pair 16B/lane nontemporal, prefetch (NT), MFMA
#define ITER1O(IIV, AJA, AJB)                                            \
  { const int II = (IIV);                                                \
    PACK(AJA, AJB, pk0, pk1)                                             \
    u32x4 pv; pv[0] = pk0_sv; pv[1] = pk1_sv; pv[2] = pk0; pv[3] = pk1;  \
    __builtin_nontemporal_store(pv,                                      \
        (u32x4*)(a8w + (size_t)((t << 2) + (II >> 1)) * 1024));          \
    unsigned long long av = (unsigned long long)pk0 | ((unsigned long long)pk1 << 32); \
    int ci = ((t << 3) + II + 4) & 127;                                  \
    AJA = __builtin_nontemporal_load((const f32x4*)(ap + (size_t)ci * 32));     \
    AJB = __builtin_nontemporal_load((const f32x4*)(ap + (size_t)ci * 32 + 4)); \
    MFMA4(av)                                                            \
  }

  for (int t = 0; t < NCH; ++t) {
    const unsigned char* bb = Blds + (t & 1) * (64 * LDST8);
    if (t + 1 < NCH) STAGE_LOAD8((t + 1) * BK);
    ITER1E(0, aj0a, aj0b)
    ITER1O(1, aj1a, aj1b)
    ITER1E(2, aj2a, aj2b)
    ITER1O(3, aj3a, aj3b)
    ITER1E(4, aj0a, aj0b)
    ITER1O(5, aj1a, aj1b)
    ITER1E(6, aj2a, aj2b)
    ITER1O(7, aj3a, aj3b)
    if (t + 1 < NCH) STAGE_WRITE8((t + 1) & 1);
    __syncthreads();
  }

  // D layout: col = lane&15 (+16*f), row = (lane>>4)*4 + reg  [m89-verified]
  int zr = (xb << 6) + (w << 4) + (kgrp << 2);
  float* pp = P + (size_t)yb * NV * 64 + (size_t)zr * 64 + l15;
  #pragma unroll
  for (int r = 0; r < 4; ++r) {
    pp[(size_t)r * 64 +  0] = acc0[r] * SCDN;
    pp[(size_t)r * 64 + 16] = acc1[r] * SCDN;
    pp[(size_t)r * 64 + 32] = acc2[r] * SCDN;
    pp[(size_t)r * 64 + 48] = acc3[r] * SCDN;
  }
#undef ITER1E
#undef ITER1O
#undef PACK
#undef MFMA4
}

// layer-2 big: P[yb] = (adj8 * 2^-14) @ B2 (fp8_fp8). adj8 pair-major,
// NONTEMPORAL loads (zero reuse); one 16B/lane load feeds TWO ITERs.
__global__ __launch_bounds__(256, 4) void k_adj8(
    const unsigned char* __restrict__ adj8, const unsigned char* __restrict__ Btq,
    float* __restrict__ P) {
  __shared__ __align__(16) unsigned char Blds[2 * 64 * LDST8];
  const int tid = threadIdx.x;
  const int lane = tid & 63;
  const int w = tid >> 6;
  const int l15 = lane & 15;
  const int kgrp = lane >> 4;
  const int xb = blockIdx.x;
  const int yb = blockIdx.y;
  const int kbase = yb << 12;

  const int srow = tid >> 4;
  const int sc16 = tid & 15;
  const unsigned char* sbase = Btq + (size_t)srow * BTQS + kbase + sc16 * 16;
  unsigned char* lbase = Blds + srow * LDST8 + sc16 * 16;

  const unsigned char* ap8 = adj8 +
      ((((size_t)xb * 4 + yb) * 4 + w) * 64) * 1024 + (size_t)lane * 16;
  const int bofs0 = (l15 +  0) * LDST8 + kgrp * 8;
  const int bofs1 = (l15 + 16) * LDST8 + kgrp * 8;
  const int bofs2 = (l15 + 32) * LDST8 + kgrp * 8;
  const int bofs3 = (l15 + 48) * LDST8 + kgrp * 8;

  f32x4 sr0, sr1, sr2, sr3;

  STAGE_LOAD8(0);
  u32x4 pr0 = __builtin_nontemporal_load((const u32x4*)(ap8 +    0));
  u32x4 pr1 = __builtin_nontemporal_load((const u32x4*)(ap8 + 1024));
  u32x4 pr2 = __builtin_nontemporal_load((const u32x4*)(ap8 + 2048));
  u32x4 pr3 = __builtin_nontemporal_load((const u32x4*)(ap8 + 3072));
  STAGE_WRITE8(0);
  __syncthreads();

  f32x4 acc0 = {0.f, 0.f, 0.f, 0.f};
  f32x4 acc1 = {0.f, 0.f, 0.f, 0.f};
  f32x4 acc2 = {0.f, 0.f, 0.f, 0.f};
  f32x4 acc3 = {0.f, 0.f, 0.f, 0.f};

#define MFMA4A(AV, II)                                                   \
    { long long a_ = (AV);                                               \
      long long b0 = *(const long long*)(bb + bofs0 + (II) * 32);        \
      long long b1 = *(const long long*)(bb + bofs1 + (II) * 32);        \
      long long b2 = *(const long long*)(bb + bofs2 + (II) * 32);        \
      long long b3 = *(const long long*)(bb + bofs3 + (II) * 32);        \
      acc0 = __builtin_amdgcn_mfma_f32_16x16x32_fp8_fp8(a_, b0, acc0, 0, 0, 0); \
      acc1 = __builtin_amdgcn_mfma_f32_16x16x32_fp8_fp8(a_, b1, acc1, 0, 0, 0); \
      acc2 = __builtin_amdgcn_mfma_f32_16x16x32_fp8_fp8(a_, b2, acc2, 0, 0, 0); \
      acc3 = __builtin_amdgcn_mfma_f32_16x16x32_fp8_fp8(a_, b3, acc3, 0, 0, 0); }

#define PITER(PP, PR)                                                    \
  {                                                                      \
    long long aE = (long long)(((unsigned long long)PR[1] << 32) | PR[0]); \
    long long aO = (long long)(((unsigned long long)PR[3] << 32) | PR[2]); \
    int ci = ((t << 2) + (PP) + 4) & 63;                                 \
    PR = __builtin_nontemporal_load((const u32x4*)(ap8 + (size_t)ci * 1024)); \
    MFMA4A(aE, 2 * (PP))                                                 \
    MFMA4A(aO, 2 * (PP) + 1)                                             \
  }

  for (int t = 0; t < NCH; ++t) {
    const unsigned char* bb = Blds + (t & 1) * (64 * LDST8);
    if (t + 1 < NCH) STAGE_LOAD8((t + 1) * BK);
    PITER(0, pr0)
    PITER(1, pr1)
    PITER(2, pr2)
    PITER(3, pr3)
    if (t + 1 < NCH) STAGE_WRITE8((t + 1) & 1);
    __syncthreads();
  }

  int zr = (xb << 6) + (w << 4) + (kgrp << 2);
  float* pp = P + (size_t)yb * NV * 64 + (size_t)zr * 64 + l15;
  #pragma unroll
  for (int r = 0; r < 4; ++r) {
    pp[(size_t)r * 64 +  0] = acc0[r] * SCDN;
    pp[(size_t)r * 64 + 16] = acc1[r] * SCDN;
    pp[(size_t)r * 64 + 32] = acc2[r] * SCDN;
    pp[(size_t)r * 64 + 48] = acc3[r] * SCDN;
  }
#undef PITER
#undef MFMA4A
#undef STAGE_LOAD8
#undef STAGE_WRITE8
}

// mid: x = relu((Z+ΣP)*rw1[reg]+rb1[reg]); Z = x@W2; Btq2 = fp8((x@L2)^T)
__global__ __launch_bounds__(256) void k_mid(
    float* __restrict__ Z, const float* __restrict__ P,
    const int* __restrict__ reg,
    const float* __restrict__ rw1, const float* __restrict__ rb1,
    const float* __restrict__ W2, const float* __restrict__ L2,
    unsigned char* __restrict__ Btq2) {
  __shared__ float Ws[4096], Ls[4096], xs[16 * 64];
  int tid = threadIdx.x;
  for (int i = tid; i < 4096; i += 256) { Ws[i] = W2[i]; Ls[i] = L2[i]; }
  int r = tid >> 6, c = tid & 63;
  int i0 = blockIdx.x << 4;
  #pragma unroll
  for (int m = 0; m < 4; ++m) {
    int i = i0 + r + 4 * m;
    int ri = reg[i];
    size_t o = (size_t)i * 64 + c;
    float z = Z[o] + P[o] + P[(size_t)NV * 64 + o] +
              P[(size_t)2 * NV * 64 + o] + P[(size_t)3 * NV * 64 + o];
    float x = z * rw1[ri * 64 + c] + rb1[ri * 64 + c];
    xs[(r + 4 * m) * 64 + c] = fmaxf(x, 0.f);
  }
  __syncthreads();
  float a1[4] = {0.f, 0.f, 0.f, 0.f};
  float a2[4] = {0.f, 0.f, 0.f, 0.f};
  #pragma unroll 8
  for (int k = 0; k < 64; ++k) {
    float wv = Ws[k * 64 + c];
    float lv = Ls[k * 64 + c];
    #pragma unroll
    for (int m = 0; m < 4; ++m) {
      float xv = xs[(r + 4 * m) * 64 + k];
      a1[m] += xv * wv;
      a2[m] += xv * lv;
    }
  }
  #pragma unroll
  for (int m = 0; m < 4; ++m) {
    int i = i0 + r + 4 * m;
    Z[(size_t)i * 64 + c] = a1[m];
    unsigned q = __builtin_amdgcn_cvt_pk_fp8_f32(a2[m], 0.0f, 0, false);
    Btq2[(size_t)c * BTQS + i] = (unsigned char)(q & 0xff);
  }
}

// out: x2 = relu((Z+ΣP)*rw2[reg]+rb2[reg]); out = x2 @ Wout^T + bout
__global__ __launch_bounds__(256) void k_out(
    const float* __restrict__ Z, const float* __restrict__ P,
    const int* __restrict__ reg,
    const float* __restrict__ rw2, const float* __restrict__ rb2,
    const float* __restrict__ Wout, const float* __restrict__ bout,
    float* __restrict__ out) {
  __shared__ float xs[16 * 64];
  int tid = threadIdx.x;
  int r = tid >> 6, c = tid & 63;
  int i0 = blockIdx.x << 4;
  #pragma unroll
  for (int m = 0; m < 4; ++m) {
    int i = i0 + r + 4 * m;
    int ri = reg[i];
    size_t o = (size_t)i * 64 + c;
    float z = Z[o] + P[o] + P[(size_t)NV * 64 + o] +
              P[(size_t)2 * NV * 64 + o] + P[(size_t)3 * NV * 64 + o];
    float x = z * rw2[ri * 64 + c] + rb2[ri * 64 + c];
    xs[(r + 4 * m) * 64 + c] = fmaxf(x, 0.f);
  }
  __syncthreads();
  if (c < 8) {
    #pragma unroll
    for (int m = 0; m < 4; ++m) {
      int i = i0 + r + 4 * m;
      float a = bout[c];
      #pragma unroll 8
      for (int k = 0; k < 64; ++k) a += xs[(r + 4 * m) * 64 + k] * Wout[c * 64 + k];
      out[(size_t)i * 8 + c] = a;
    }
  }
}

extern "C" void kernel_launch(void* const* d_in, const int* in_sizes, int n_in,
                              void* d_out, int out_size, void* d_ws, size_t ws_size,
                              hipStream_t stream) {
  const float* h    = (const float*)d_in[0];
  const float* adj  = (const float*)d_in[1];
  const int*   reg  = (const int*)d_in[2];
  const float* W1   = (const float*)d_in[3];
  const float* L1   = (const float*)d_in[4];
  const float* rw1  = (const float*)d_in[5];
  const float* rb1  = (const float*)d_in[6];
  const float* W2   = (const float*)d_in[7];
  const float* L2   = (const float*)d_in[8];
  const float* rw2  = (const float*)d_in[9];
  const float* rb2  = (const float*)d_in[10];
  const float* Wout = (const float*)d_in[11];
  const float* bout = (const float*)d_in[12];
  float* out = (float*)d_out;

  char* ws = (char*)d_ws;
  float* Z            = (float*)(ws);                                 // 4 MB @ 0
  unsigned char* Btq1 = (unsigned char*)(ws + ((size_t)4  << 20));    // ~1.06 MB
  float* P            = (float*)(ws + ((size_t)8  << 20));            // 16 MB (4 slices)
  unsigned char* Btq2 = (unsigned char*)(ws + ((size_t)24 << 20));    // ~1.06 MB
  unsigned char* adj8 = (unsigned char*)(ws + ((size_t)28 << 20));    // 256 MB

  k_prep<<<NV / 16, 256, 0, stream>>>(h, W1, L1, Z, Btq1);
  k_adj1<<<dim3(NV / 64, 4), 256, 0, stream>>>(adj, Btq1, P, adj8);
  k_mid<<<NV / 16, 256, 0, stream>>>(Z, P, reg, rw1, rb1, W2, L2, Btq2);
  k_adj8<<<dim3(NV / 64, 4), 256, 0, stream>>>(adj8, Btq2, P);
  k_out<<<NV / 16, 256, 0, stream>>>(Z, P, reg, rw2, rb2, Wout, bout, out);
}